// Round 3
// baseline (132.655 us; speedup 1.0000x reference)
//
#include <hip/hip_runtime.h>
#include <hip/hip_cooperative_groups.h>
#include <math.h>

namespace cg = cooperative_groups;

// MinusAttention: score(i,j) = (w.q_i - w.k_j + b)/sqrt(E), causal softmax, @V.
// Softmax cancels the per-row (w.q_i + b) constant -> weights depend only on keys:
//   out[i] = prefix_{j<=i}(e_j * v_j) / prefix_{j<=i}(e_j),  e_j = exp(-(w.k_j)/8).
// Single cooperative kernel: per-chunk partials -> grid sync -> prefix + downsweep.
// Values chunk lives in registers across the sync (no HBM re-read).

#define B_  4
#define L_  2048
#define S_  2048
#define H_  8
#define E_  64
#define BH_ (B_ * H_)
#define CS_ 32                 // rows per chunk (per block)
#define NC_ (S_ / CS_)         // 64 chunks per (b,h)
#define NBLK (BH_ * NC_)       // 2048 blocks, 64 threads each -> 8 blocks/CU

__global__ __launch_bounds__(64) void k_fused(const float* __restrict__ keys,
                                              const float* __restrict__ values,
                                              const float* __restrict__ w,
                                              float* __restrict__ cden,
                                              float* __restrict__ cnum,
                                              float* __restrict__ out) {
    const int idx = blockIdx.x;
    const int bh  = idx / NC_, c = idx % NC_;
    const int b   = bh / H_,   h = bh % H_;
    const int t   = threadIdx.x;
    const int cf  = t & 15;    // float4 column within a 64-elem row
    const int rq  = t >> 4;    // row-in-group (4 rows per pass)

    __shared__ float e_lds[CS_];

    const size_t row0 = (size_t)b * S_ + (size_t)c * CS_;

    // ---- scores for this chunk: e_j = exp(-(w.k_j)/8) ----
    const float4 w4 = reinterpret_cast<const float4*>(w)[cf];
    const float* kbase = keys + (row0 * H_ + h) * (size_t)E_;
    #pragma unroll
    for (int g = 0; g < CS_ / 4; ++g) {
        const int r = g * 4 + rq;
        const float4 kv = *reinterpret_cast<const float4*>(
            kbase + (size_t)r * (H_ * E_) + cf * 4);
        float p = kv.x * w4.x + kv.y * w4.y + kv.z * w4.z + kv.w * w4.w;
        p += __shfl_xor(p, 1);
        p += __shfl_xor(p, 2);
        p += __shfl_xor(p, 4);
        p += __shfl_xor(p, 8);
        if (cf == 0) e_lds[r] = __expf(-p * 0.125f);
    }
    __syncthreads();

    // ---- values chunk -> registers (stay live across grid sync) ----
    const float* vp = values + (row0 * H_ + h) * (size_t)E_ + t;
    float v_r[CS_];
    #pragma unroll
    for (int jj = 0; jj < CS_; ++jj) v_r[jj] = vp[(size_t)jj * (H_ * E_)];

    // ---- chunk partial sums ----
    float num = 0.f, den = 0.f;
    #pragma unroll
    for (int jj = 0; jj < CS_; ++jj) {
        const float e = e_lds[jj];
        num = fmaf(e, v_r[jj], num);
        den += e;
    }
    cnum[(size_t)idx * E_ + t] = num;
    if (t == 0) cden[idx] = den;

    cg::this_grid().sync();

    // ---- exclusive prefix over predecessor chunks (same bh) ----
    float pnum = 0.f, pden = 0.f;
    for (int cp = bh * NC_; cp < idx; ++cp) {
        pnum += cnum[(size_t)cp * E_ + t];   // coalesced 256B, L2/L3-hot
        pden += cden[cp];                    // broadcast
    }

    // ---- in-chunk downsweep from registers, write out ----
    float* op = out + (row0 * H_ + h) * (size_t)E_ + t;   // L_ == S_
    #pragma unroll
    for (int jj = 0; jj < CS_; ++jj) {
        const float e = e_lds[jj];
        pnum = fmaf(e, v_r[jj], pnum);
        pden += e;
        op[(size_t)jj * (H_ * E_)] = pnum / pden;
    }
}

extern "C" void kernel_launch(void* const* d_in, const int* in_sizes, int n_in,
                              void* d_out, int out_size, void* d_ws, size_t ws_size,
                              hipStream_t stream) {
    // inputs: 0=queries (UNUSED), 1=keys, 2=values, 3=w_score,
    //         4=b_score (cancels), 5=attn_mask (sentinel -> causal)
    const float* keys   = (const float*)d_in[1];
    const float* values = (const float*)d_in[2];
    const float* w      = (const float*)d_in[3];
    float* out = (float*)d_out;

    // workspace: cnum[NBLK*E] | cden[NBLK]   (~520 KB)
    float* cnum = (float*)d_ws;
    float* cden = cnum + (size_t)NBLK * E_;

    void* args[] = {(void*)&keys, (void*)&values, (void*)&w,
                    (void*)&cden, (void*)&cnum, (void*)&out};
    hipLaunchCooperativeKernel((const void*)k_fused, dim3(NBLK), dim3(64),
                               args, 0, stream);
}

// Round 4
// 20.462 us; speedup vs baseline: 6.4830x; 6.4830x over previous
//
#include <hip/hip_runtime.h>
#include <math.h>

// MinusAttention: score(i,j) = (w.q_i - w.k_j + b)/sqrt(E), causal softmax, @V.
// Softmax cancels the per-row (w.q_i + b) constant -> weights depend only on keys:
//   out[i] = prefix_{j<=i}(e_j * v_j) / prefix_{j<=i}(e_j),  e_j = exp(-(w.k_j)/8).
// Two kernels (no grid sync — coop sync measured slower than an L3-hot re-read):
//   K1: per-chunk scores e_j + chunk partial sums (upsweep)
//   K2: exclusive prefix over earlier chunks + in-chunk downsweep + output
// Chunk = 32 rows, one wave per chunk, 4 waves per block.

#define B_  4
#define L_  2048
#define S_  2048
#define H_  8
#define E_  64
#define BH_ (B_ * H_)
#define CS_ 32                 // rows per chunk (one wave per chunk)
#define NC_ (S_ / CS_)         // 64 chunks per (b,h)
#define NCHUNK (BH_ * NC_)     // 2048 chunks
#define WPB 4                  // waves per block
#define NBLK (NCHUNK / WPB)    // 512 blocks x 256 threads

// K1: e[idx*CS + r] = exp(-(w.k)/8); cnum[idx*E + c] = sum_r e_r v[r,c]; cden[idx] = sum_r e_r
__global__ __launch_bounds__(256) void k_part(const float* __restrict__ keys,
                                              const float* __restrict__ values,
                                              const float* __restrict__ w,
                                              float* __restrict__ e_g,
                                              float* __restrict__ cden,
                                              float* __restrict__ cnum) {
    const int wave = threadIdx.x >> 6, lane = threadIdx.x & 63;
    const int idx = blockIdx.x * WPB + wave;          // chunk id
    const int bh = idx / NC_, c = idx % NC_;
    const int b  = bh / H_,  h = bh % H_;
    const int cf = lane & 15;                         // float4 col within 64-elem row
    const int rq = lane >> 4;                         // 4 rows per pass

    __shared__ float e_lds[WPB][CS_];

    const size_t row0 = (size_t)b * S_ + (size_t)c * CS_;
    const float4 w4 = reinterpret_cast<const float4*>(w)[cf];
    const float* kbase = keys + (row0 * H_ + h) * (size_t)E_;

    #pragma unroll
    for (int g = 0; g < CS_ / 4; ++g) {
        const int r = g * 4 + rq;
        const float4 kv = *reinterpret_cast<const float4*>(
            kbase + (size_t)r * (H_ * E_) + cf * 4);
        float p = kv.x * w4.x + kv.y * w4.y + kv.z * w4.z + kv.w * w4.w;
        p += __shfl_xor(p, 1);
        p += __shfl_xor(p, 2);
        p += __shfl_xor(p, 4);
        p += __shfl_xor(p, 8);
        if (cf == 0) e_lds[wave][r] = __expf(-p * 0.125f);
    }
    __syncthreads();

    const float* vp = values + (row0 * H_ + h) * (size_t)E_ + lane;
    float num = 0.f, den = 0.f;
    #pragma unroll
    for (int jj = 0; jj < CS_; ++jj) {
        const float e = e_lds[wave][jj];
        num = fmaf(e, vp[(size_t)jj * (H_ * E_)], num);
        den += e;
    }
    cnum[(size_t)idx * E_ + lane] = num;
    if (lane == 0) cden[idx] = den;
    if (lane < CS_) e_g[(size_t)idx * CS_ + lane] = e_lds[wave][lane];
}

// K2: prefix over earlier chunks of this (b,h), then downsweep + out.
__global__ __launch_bounds__(256) void k_scan(const float* __restrict__ values,
                                              const float* __restrict__ e_g,
                                              const float* __restrict__ cden,
                                              const float* __restrict__ cnum,
                                              float* __restrict__ out) {
    const int wave = threadIdx.x >> 6, lane = threadIdx.x & 63;
    const int idx = blockIdx.x * WPB + wave;
    const int bh = idx / NC_, c = idx % NC_;
    const int b  = bh / H_,  h = bh % H_;

    __shared__ float e_lds[WPB][CS_];
    if (lane < CS_) e_lds[wave][lane] = e_g[(size_t)idx * CS_ + lane];
    __syncthreads();

    float pnum = 0.f, pden = 0.f;
    #pragma unroll 4
    for (int cp = bh * NC_; cp < idx; ++cp) {         // uniform trip count per wave
        pnum += cnum[(size_t)cp * E_ + lane];         // 256B coalesced, L2/L3-hot
        pden += cden[cp];                             // scalar broadcast
    }

    const size_t row0 = (size_t)b * S_ + (size_t)c * CS_;
    const float* vp = values + (row0 * H_ + h) * (size_t)E_ + lane;  // L3-hot
    float*       op = out    + (row0 * H_ + h) * (size_t)E_ + lane;  // L_ == S_
    #pragma unroll
    for (int jj = 0; jj < CS_; ++jj) {
        const float e = e_lds[wave][jj];
        pnum = fmaf(e, vp[(size_t)jj * (H_ * E_)], pnum);
        pden += e;
        op[(size_t)jj * (H_ * E_)] = pnum * __builtin_amdgcn_rcpf(pden);
    }
}

extern "C" void kernel_launch(void* const* d_in, const int* in_sizes, int n_in,
                              void* d_out, int out_size, void* d_ws, size_t ws_size,
                              hipStream_t stream) {
    // inputs: 0=queries (UNUSED), 1=keys, 2=values, 3=w_score,
    //         4=b_score (cancels), 5=attn_mask (sentinel -> causal)
    const float* keys   = (const float*)d_in[1];
    const float* values = (const float*)d_in[2];
    const float* w      = (const float*)d_in[3];
    float* out = (float*)d_out;

    // workspace (floats): e_g[NCHUNK*CS] | cnum[NCHUNK*E] | cden[NCHUNK]
    float* e_g  = (float*)d_ws;
    float* cnum = e_g + (size_t)NCHUNK * CS_;
    float* cden = cnum + (size_t)NCHUNK * E_;

    hipLaunchKernelGGL(k_part, dim3(NBLK), dim3(256), 0, stream,
                       keys, values, w, e_g, cden, cnum);
    hipLaunchKernelGGL(k_scan, dim3(NBLK), dim3(256), 0, stream,
                       values, e_g, cden, cnum, out);
}